// Round 1
// baseline (966.265 us; speedup 1.0000x reference)
//
#include <hip/hip_runtime.h>
#include <hip/hip_bf16.h>
#include <math.h>

#define N_NODES 50000
#define N_EDGES 800000
#define EPS 1e-5f
#define SLOPE 0.2f

typedef unsigned int u32;
typedef unsigned short u16;

__device__ __forceinline__ float bf2f(u16 v) {
    u32 u = ((u32)v) << 16;
    return __uint_as_float(u);
}
__device__ __forceinline__ u16 f2bf(float f) {
    u32 u = __float_as_uint(f);
    u32 r = (u + 0x7fffu + ((u >> 16) & 1u)) >> 16;  // RNE
    return (u16)r;
}
__device__ __forceinline__ float wred(float v) {
    #pragma unroll
    for (int off = 32; off > 0; off >>= 1) v += __shfl_xor(v, off, 64);
    return v;
}

// ---- M[k][l*4+h] = sum_c gat_ew[l][k][h*32+c] * gat_ae[l][h][c] ----
__global__ void k_M(const float* __restrict__ ew, const float* __restrict__ ae,
                    float* __restrict__ M) {
    int t = threadIdx.x;
    if (t >= 768) return;
    int k = t / 12, j = t % 12;
    int l = j >> 2, h = j & 3;
    const float* ewp = ew + l * 8192 + k * 128 + h * 32;
    const float* aep = ae + l * 128 + h * 32;
    float s = 0.f;
    #pragma unroll
    for (int c = 0; c < 32; c++) s += ewp[c] * aep[c];
    M[k * 12 + j] = s;
}

// ---- node preprocess: h = relu(LN(x @ np_w + np_b)) ; wave per node ----
__global__ __launch_bounds__(256) void k_node_pre(
        const float* __restrict__ x, const float* __restrict__ w,
        const float* __restrict__ b, const float* __restrict__ g,
        const float* __restrict__ be, float* __restrict__ h) {
    int wave = threadIdx.x >> 6, lane = threadIdx.x & 63;
    int n = blockIdx.x * 4 + wave;
    if (n >= N_NODES) return;
    const float* xr = x + (size_t)n * 16;
    float xv[16];
    #pragma unroll
    for (int k = 0; k < 16; k++) xv[k] = xr[k];
    int c0 = lane, c1 = lane + 64;
    float a0 = b[c0], a1 = b[c1];
    #pragma unroll
    for (int k = 0; k < 16; k++) {
        a0 = fmaf(xv[k], w[k * 128 + c0], a0);
        a1 = fmaf(xv[k], w[k * 128 + c1], a1);
    }
    float m = wred(a0 + a1) * (1.f / 128.f);
    float d0 = a0 - m, d1 = a1 - m;
    float v = wred(d0 * d0 + d1 * d1) * (1.f / 128.f);
    float rs = rsqrtf(v + EPS);
    float o0 = d0 * rs * g[c0] + be[c0];
    float o1 = d1 * rs * g[c1] + be[c1];
    h[(size_t)n * 128 + c0] = fmaxf(o0, 0.f);
    h[(size_t)n * 128 + c1] = fmaxf(o1, 0.f);
}

// ---- degree count ----
__global__ void k_deg(const int* __restrict__ dst, int* __restrict__ deg) {
    int e = blockIdx.x * 256 + threadIdx.x;
    if (e < N_EDGES) atomicAdd(&deg[dst[e]], 1);
}

// ---- 3-phase exclusive scan -> rowptr ----
__global__ void k_scan1(const int* __restrict__ deg, int* __restrict__ incl,
                        int* __restrict__ bsum) {
    __shared__ int lds[1024];
    int i = blockIdx.x * 1024 + threadIdx.x;
    int v = (i < N_NODES) ? deg[i] : 0;
    lds[threadIdx.x] = v;
    __syncthreads();
    for (int off = 1; off < 1024; off <<= 1) {
        int t = (threadIdx.x >= off) ? lds[threadIdx.x - off] : 0;
        __syncthreads();
        lds[threadIdx.x] += t;
        __syncthreads();
    }
    if (i < N_NODES) incl[i] = lds[threadIdx.x];
    if (threadIdx.x == 1023) bsum[blockIdx.x] = lds[1023];
}
__global__ void k_scan2(int* __restrict__ bsum, int nb) {
    if (threadIdx.x == 0 && blockIdx.x == 0) {
        int run = 0;
        for (int i = 0; i < nb; i++) { int t = bsum[i]; bsum[i] = run; run += t; }
    }
}
__global__ void k_scan3(const int* __restrict__ incl, const int* __restrict__ bsum,
                        int* __restrict__ rowptr) {
    int i = blockIdx.x * 1024 + threadIdx.x;
    if (i < N_NODES) rowptr[i + 1] = incl[i] + bsum[blockIdx.x];
    if (i == 0) rowptr[0] = 0;
}

// ---- fused edge preprocess + alphaE (3 layers x 4 heads) + CSR fill ----
__global__ __launch_bounds__(256) void k_edge(
        const int* __restrict__ ei, const float* __restrict__ ea,
        const float* __restrict__ epw, const float* __restrict__ epb,
        const float* __restrict__ epg, const float* __restrict__ epbe,
        const float* __restrict__ M, const int* __restrict__ rowptr,
        int* __restrict__ cursor, int* __restrict__ csr_src,
        float* __restrict__ csr_aE) {
    __shared__ float sW[512], sM[768], sB[64], sG[64], sBe[64];
    for (int i = threadIdx.x; i < 512; i += 256) sW[i] = epw[i];
    for (int i = threadIdx.x; i < 768; i += 256) sM[i] = M[i];
    if (threadIdx.x < 64) {
        sB[threadIdx.x] = epb[threadIdx.x];
        sG[threadIdx.x] = epg[threadIdx.x];
        sBe[threadIdx.x] = epbe[threadIdx.x];
    }
    __syncthreads();
    int e = blockIdx.x * 256 + threadIdx.x;
    if (e >= N_EDGES) return;
    int src = ei[e], dst = ei[N_EDGES + e];
    float xa[8];
    #pragma unroll
    for (int k = 0; k < 8; k++) xa[k] = ea[(size_t)e * 8 + k];
    float v[64];
    float sum = 0.f;
    #pragma unroll
    for (int c = 0; c < 64; c++) {
        float a = sB[c];
        #pragma unroll
        for (int k = 0; k < 8; k++) a = fmaf(xa[k], sW[k * 64 + c], a);
        v[c] = a; sum += a;
    }
    float m = sum * (1.f / 64.f);
    float var = 0.f;
    #pragma unroll
    for (int c = 0; c < 64; c++) { float d = v[c] - m; var += d * d; }
    float rs = rsqrtf(var * (1.f / 64.f) + EPS);
    #pragma unroll
    for (int c = 0; c < 64; c++) {
        float o = (v[c] - m) * rs * sG[c] + sBe[c];
        v[c] = fmaxf(o, 0.f);
    }
    float aE[12];
    #pragma unroll
    for (int j = 0; j < 12; j++) aE[j] = 0.f;
    #pragma unroll
    for (int c = 0; c < 64; c++) {
        float vc = v[c];
        #pragma unroll
        for (int j = 0; j < 12; j++) aE[j] = fmaf(vc, sM[c * 12 + j], aE[j]);
    }
    int slot = rowptr[dst] + atomicAdd(&cursor[dst], 1);
    csr_src[slot] = src;
    #pragma unroll
    for (int j = 0; j < 12; j++) csr_aE[(size_t)slot * 12 + j] = aE[j];
}

// ---- GEMM xs = h @ W  (bf16 out), W staged fp32 in LDS (two halves) ----
__global__ __launch_bounds__(256) void k_gemm_xs(
        const float* __restrict__ h, const float* __restrict__ W,
        u16* __restrict__ xs) {
    __shared__ float2 sW[64 * 64];   // 32 KB: k-half x 64 channel-pairs
    __shared__ float sH[16][128];    // 8 KB
    int tid = threadIdx.x;
    int base = blockIdx.x * 16;
    for (int i = tid; i < 2048; i += 256) {
        int r = i >> 7, c = i & 127;
        int n = base + r;
        sH[r][c] = (n < N_NODES) ? h[(size_t)n * 128 + c] : 0.f;
    }
    int wave = tid >> 6, lane = tid & 63;
    float acc[4][2];
    #pragma unroll
    for (int r = 0; r < 4; r++) { acc[r][0] = 0.f; acc[r][1] = 0.f; }
    for (int half = 0; half < 2; half++) {
        __syncthreads();
        for (int i = tid; i < 4096; i += 256) {
            int k = (i >> 6) + half * 64, j = i & 63;
            sW[i] = make_float2(W[k * 128 + j], W[k * 128 + j + 64]);
        }
        __syncthreads();
        #pragma unroll 8
        for (int k2 = 0; k2 < 64; k2++) {
            float2 wv = sW[k2 * 64 + lane];
            int k = half * 64 + k2;
            #pragma unroll
            for (int r = 0; r < 4; r++) {
                float hk = sH[wave * 4 + r][k];
                acc[r][0] = fmaf(hk, wv.x, acc[r][0]);
                acc[r][1] = fmaf(hk, wv.y, acc[r][1]);
            }
        }
    }
    #pragma unroll
    for (int r = 0; r < 4; r++) {
        int n = base + wave * 4 + r;
        if (n < N_NODES) {
            xs[(size_t)n * 128 + lane]      = f2bf(acc[r][0]);
            xs[(size_t)n * 128 + lane + 64] = f2bf(acc[r][1]);
        }
    }
}

// ---- al_s / al_d per (node, head) ----
__global__ void k_al(const u16* __restrict__ xs, const float* __restrict__ as_,
                     const float* __restrict__ ad_, float* __restrict__ al_s,
                     float* __restrict__ al_d) {
    int t = blockIdx.x * 256 + threadIdx.x;
    if (t >= N_NODES * 4) return;
    int n = t >> 2, hh = t & 3;
    const u16* xp = xs + (size_t)n * 128 + hh * 32;
    const float* ap = as_ + hh * 32;
    const float* dp = ad_ + hh * 32;
    float s = 0.f, d = 0.f;
    #pragma unroll
    for (int c = 0; c < 32; c++) {
        float xv = bf2f(xp[c]);
        s = fmaf(xv, ap[c], s);
        d = fmaf(xv, dp[c], d);
    }
    al_s[t] = s; al_d[t] = d;
}

// ---- GAT aggregation: wave per node, softmax (shift-free) + self-loop ----
__global__ __launch_bounds__(256) void k_agg(
        const int* __restrict__ rowptr, const int* __restrict__ csr_src,
        const float* __restrict__ csr_aE, const float* __restrict__ al_s,
        const float* __restrict__ al_d, const u16* __restrict__ xs,
        const float* __restrict__ bias, float* __restrict__ outp, int l4) {
    int wave = threadIdx.x >> 6, lane = threadIdx.x & 63;
    int n = blockIdx.x * 4 + wave;
    if (n >= N_NODES) return;
    int row = rowptr[n], end = rowptr[n + 1];
    int h0 = lane >> 5, h1 = h0 + 2;
    int c0 = lane, c1 = lane + 64;
    float ald0 = al_d[n * 4 + h0], ald1 = al_d[n * 4 + h1];
    float asn0 = al_s[n * 4 + h0], asn1 = al_s[n * 4 + h1];
    float xn0 = bf2f(xs[(size_t)n * 128 + c0]);
    float xn1 = bf2f(xs[(size_t)n * 128 + c1]);
    float acc0 = 0.f, acc1 = 0.f, s0 = 0.f, s1 = 0.f, aes0 = 0.f, aes1 = 0.f;
    for (int slot = row; slot < end; slot++) {
        int srcv = csr_src[slot];
        float ae0 = csr_aE[(size_t)slot * 12 + l4 + h0];
        float ae1 = csr_aE[(size_t)slot * 12 + l4 + h1];
        float as0 = al_s[srcv * 4 + h0];
        float as1 = al_s[srcv * 4 + h1];
        aes0 += ae0; aes1 += ae1;
        float a0 = as0 + ald0 + ae0; a0 = (a0 >= 0.f) ? a0 : SLOPE * a0;
        float a1 = as1 + ald1 + ae1; a1 = (a1 >= 0.f) ? a1 : SLOPE * a1;
        float e0 = __expf(a0), e1 = __expf(a1);
        s0 += e0; s1 += e1;
        acc0 = fmaf(e0, bf2f(xs[(size_t)srcv * 128 + c0]), acc0);
        acc1 = fmaf(e1, bf2f(xs[(size_t)srcv * 128 + c1]), acc1);
    }
    // self-loop (PyG add_self_loops, fill_value='mean'): aE = mean over row
    float dinv = 1.f / fmaxf((float)(end - row), 1.f);
    float sa0 = asn0 + ald0 + aes0 * dinv; sa0 = (sa0 >= 0.f) ? sa0 : SLOPE * sa0;
    float sa1 = asn1 + ald1 + aes1 * dinv; sa1 = (sa1 >= 0.f) ? sa1 : SLOPE * sa1;
    float e0 = __expf(sa0), e1 = __expf(sa1);
    s0 += e0; s1 += e1;
    acc0 = fmaf(e0, xn0, acc0);
    acc1 = fmaf(e1, xn1, acc1);
    outp[(size_t)n * 128 + c0] = acc0 / s0 + bias[c0];
    outp[(size_t)n * 128 + c1] = acc1 / s1 + bias[c1];
}

// ---- BN stats (sum, sumsq per channel) ----
__global__ void k_bn_stats(const float* __restrict__ x, float* __restrict__ stats) {
    __shared__ float lds[512];
    int t = threadIdx.x;
    int c = t & 127, half = t >> 7;
    float s = 0.f, q = 0.f;
    for (int n = blockIdx.x * 2 + half; n < N_NODES; n += gridDim.x * 2) {
        float v = x[(size_t)n * 128 + c];
        s += v; q = fmaf(v, v, q);
    }
    lds[t] = s; lds[256 + t] = q;
    __syncthreads();
    if (t < 128) {
        atomicAdd(&stats[c], lds[t] + lds[t + 128]);
        atomicAdd(&stats[128 + c], lds[256 + t] + lds[256 + t + 128]);
    }
}

// ---- BN finalize + residual + relu (writes h in-place) ----
__global__ void k_bn_apply(const float* __restrict__ outp, const float* __restrict__ stats,
                           const float* __restrict__ g, const float* __restrict__ b,
                           float* __restrict__ h) {
    int idx = blockIdx.x * 256 + threadIdx.x;
    if (idx >= N_NODES * 128) return;
    int c = idx & 127;
    float m = stats[c] * (1.f / N_NODES);
    float var = stats[128 + c] * (1.f / N_NODES) - m * m;
    float rs = rsqrtf(var + EPS);
    float v = (outp[idx] - m) * rs * g[c] + b[c] + h[idx];
    h[idx] = fmaxf(v, 0.f);
}

// ---- final proj GEMM + LN -> d_out ----
__global__ __launch_bounds__(256) void k_gemm_fp(
        const float* __restrict__ h, const float* __restrict__ W,
        const float* __restrict__ fb, const float* __restrict__ g,
        const float* __restrict__ be, float* __restrict__ out) {
    __shared__ float2 sW[64 * 64];
    __shared__ float sH[16][128];
    int tid = threadIdx.x;
    int base = blockIdx.x * 16;
    for (int i = tid; i < 2048; i += 256) {
        int r = i >> 7, c = i & 127;
        int n = base + r;
        sH[r][c] = (n < N_NODES) ? h[(size_t)n * 128 + c] : 0.f;
    }
    int wave = tid >> 6, lane = tid & 63;
    float acc[4][2];
    #pragma unroll
    for (int r = 0; r < 4; r++) { acc[r][0] = 0.f; acc[r][1] = 0.f; }
    for (int half = 0; half < 2; half++) {
        __syncthreads();
        for (int i = tid; i < 4096; i += 256) {
            int k = (i >> 6) + half * 64, j = i & 63;
            sW[i] = make_float2(W[k * 128 + j], W[k * 128 + j + 64]);
        }
        __syncthreads();
        #pragma unroll 8
        for (int k2 = 0; k2 < 64; k2++) {
            float2 wv = sW[k2 * 64 + lane];
            int k = half * 64 + k2;
            #pragma unroll
            for (int r = 0; r < 4; r++) {
                float hk = sH[wave * 4 + r][k];
                acc[r][0] = fmaf(hk, wv.x, acc[r][0]);
                acc[r][1] = fmaf(hk, wv.y, acc[r][1]);
            }
        }
    }
    #pragma unroll
    for (int r = 0; r < 4; r++) {
        int n = base + wave * 4 + r;
        float y0 = acc[r][0] + fb[lane];
        float y1 = acc[r][1] + fb[lane + 64];
        float m = wred(y0 + y1) * (1.f / 128.f);
        float d0 = y0 - m, d1 = y1 - m;
        float var = wred(d0 * d0 + d1 * d1) * (1.f / 128.f);
        float rs = rsqrtf(var + EPS);
        if (n < N_NODES) {
            out[(size_t)n * 128 + lane]      = d0 * rs * g[lane] + be[lane];
            out[(size_t)n * 128 + lane + 64] = d1 * rs * g[lane + 64] + be[lane + 64];
        }
    }
}

extern "C" void kernel_launch(void* const* d_in, const int* in_sizes, int n_in,
                              void* d_out, int out_size, void* d_ws, size_t ws_size,
                              hipStream_t stream) {
    const float* x      = (const float*)d_in[0];
    const int*   ei     = (const int*)d_in[1];
    const float* ea     = (const float*)d_in[2];
    const float* np_w   = (const float*)d_in[3];
    const float* np_b   = (const float*)d_in[4];
    const float* np_g   = (const float*)d_in[5];
    const float* np_be  = (const float*)d_in[6];
    const float* ep_w   = (const float*)d_in[7];
    const float* ep_b   = (const float*)d_in[8];
    const float* ep_g   = (const float*)d_in[9];
    const float* ep_be  = (const float*)d_in[10];
    const float* gat_w  = (const float*)d_in[11];
    const float* gat_as = (const float*)d_in[12];
    const float* gat_ad = (const float*)d_in[13];
    const float* gat_ew = (const float*)d_in[14];
    const float* gat_ae = (const float*)d_in[15];
    const float* gat_b  = (const float*)d_in[16];
    const float* bn_g   = (const float*)d_in[17];
    const float* bn_b   = (const float*)d_in[18];
    const float* fp_w   = (const float*)d_in[19];
    const float* fp_b   = (const float*)d_in[20];
    const float* fp_g   = (const float*)d_in[21];
    const float* fp_be  = (const float*)d_in[22];
    float* out = (float*)d_out;

    char* ws = (char*)d_ws;
    size_t off = 0;
    auto alloc = [&](size_t bytes) -> void* {
        void* p = ws + off;
        off = (off + bytes + 255) & ~(size_t)255;
        return p;
    };
    float* h      = (float*)alloc((size_t)N_NODES * 128 * 4);
    float* buf    = (float*)alloc((size_t)N_NODES * 128 * 4);
    u16*   xs     = (u16*)alloc((size_t)N_NODES * 128 * 2);
    float* al_s   = (float*)alloc((size_t)N_NODES * 4 * 4);
    float* al_d   = (float*)alloc((size_t)N_NODES * 4 * 4);
    int*   deg    = (int*)alloc((size_t)N_NODES * 4);
    int*   rowptr = (int*)alloc((size_t)(N_NODES + 1) * 4);
    int*   cursor = (int*)alloc((size_t)N_NODES * 4);
    int*   incl   = (int*)alloc((size_t)N_NODES * 4);
    int*   bsum   = (int*)alloc(64 * 4);
    int*   csr_src= (int*)alloc((size_t)N_EDGES * 4);
    float* csr_aE = (float*)alloc((size_t)N_EDGES * 12 * 4);
    float* M      = (float*)alloc(64 * 12 * 4);
    float* stats  = (float*)alloc(256 * 4);

    hipMemsetAsync(deg, 0, (size_t)N_NODES * 4, stream);
    hipMemsetAsync(cursor, 0, (size_t)N_NODES * 4, stream);

    k_M<<<1, 768, 0, stream>>>(gat_ew, gat_ae, M);
    k_node_pre<<<(N_NODES + 3) / 4, 256, 0, stream>>>(x, np_w, np_b, np_g, np_be, h);
    k_deg<<<(N_EDGES + 255) / 256, 256, 0, stream>>>(ei + N_EDGES, deg);
    int nblk = (N_NODES + 1023) / 1024;
    k_scan1<<<nblk, 1024, 0, stream>>>(deg, incl, bsum);
    k_scan2<<<1, 64, 0, stream>>>(bsum, nblk);
    k_scan3<<<nblk, 1024, 0, stream>>>(incl, bsum, rowptr);
    k_edge<<<(N_EDGES + 255) / 256, 256, 0, stream>>>(ei, ea, ep_w, ep_b, ep_g, ep_be,
                                                      M, rowptr, cursor, csr_src, csr_aE);

    for (int l = 0; l < 3; l++) {
        k_gemm_xs<<<(N_NODES + 15) / 16, 256, 0, stream>>>(h, gat_w + (size_t)l * 16384, xs);
        k_al<<<(N_NODES * 4 + 255) / 256, 256, 0, stream>>>(xs, gat_as + l * 128,
                                                            gat_ad + l * 128, al_s, al_d);
        hipMemsetAsync(stats, 0, 256 * 4, stream);
        k_agg<<<(N_NODES + 3) / 4, 256, 0, stream>>>(rowptr, csr_src, csr_aE, al_s, al_d,
                                                     xs, gat_b + l * 128, buf, l * 4);
        k_bn_stats<<<256, 256, 0, stream>>>(buf, stats);
        k_bn_apply<<<(N_NODES * 128 + 255) / 256, 256, 0, stream>>>(buf, stats,
                                                                    bn_g + l * 128,
                                                                    bn_b + l * 128, h);
    }
    k_gemm_fp<<<(N_NODES + 15) / 16, 256, 0, stream>>>(h, fp_w, fp_b, fp_g, fp_be, out);
}